// Round 7
// baseline (421.758 us; speedup 1.0000x reference)
//
#include <hip/hip_runtime.h>
#include <hip/hip_bf16.h>
#include <stdint.h>

#define B_ 8
#define S_ 2048
#define E_ 768

typedef __attribute__((ext_vector_type(4))) float f32x4;
typedef __attribute__((ext_vector_type(8))) short bf16x8;

// GEMM core: BM=256, BN=256, BK=32, 512 thr (8 waves 2Mx4N, 128x64 per wave)
// LDS: 4 buffers x (A 16KB + B 16KB) = 128 KB, lead-3 prefetch, vmcnt(8),
// 2 fine phases per K-tile (16 MFMA each) with per-phase barrier pairs.
#define TILE_USH (256 * 32)  // 16 KB per operand per buffer

__device__ __forceinline__ unsigned pk2bf(float x, float y) {
  unsigned r;
  asm("v_cvt_pk_bf16_f32 %0, %1, %2" : "=v"(r) : "v"(x), "v"(y));
  return r;
}

__device__ __forceinline__ void gll16(const void* g, void* l) {
  __builtin_amdgcn_global_load_lds((const __attribute__((address_space(1))) void*)g,
                                   (__attribute__((address_space(3))) void*)l, 16, 0, 0);
}

// Swizzle for 64B rows (32 bf16): chunk' = chunk ^ ((row>>1)&3).
// Staging: LDS dest linear, global SOURCE pre-swizzled (involution, rule #21).
__device__ __forceinline__ void stage_op(const char* Gb, int ld, int kt,
                                         unsigned short* Ls, int tid) {
#pragma unroll
  for (int i = 0; i < 2; ++i) {
    const unsigned lin = (unsigned)i * 8192u + (unsigned)tid * 16u;
    const unsigned row = lin >> 6;
    const unsigned chunk = (lin >> 4) & 3u;
    const unsigned sw = (chunk ^ ((row >> 1) & 3u)) << 4;
    gll16(Gb + (size_t)row * ld + (size_t)kt * 64 + sw, (char*)Ls + lin);
  }
}

__device__ __forceinline__ void ldsA8(const unsigned short* As, int wm, int lane,
                                      bf16x8 (&af)[8]) {
  const unsigned ksw = (unsigned)(lane >> 4);
#pragma unroll
  for (int m = 0; m < 8; ++m) {
    const unsigned row = (unsigned)(wm * 128 + m * 16 + (lane & 15));
    const unsigned off = row * 64 + ((ksw ^ ((row >> 1) & 3u)) << 4);
    af[m] = *reinterpret_cast<const bf16x8*>((const char*)As + off);
  }
}

__device__ __forceinline__ void ldsB2(const unsigned short* Bs, int wn, int n0, int lane,
                                      bf16x8 (&bf)[2]) {
  const unsigned ksw = (unsigned)(lane >> 4);
#pragma unroll
  for (int j = 0; j < 2; ++j) {
    const unsigned row = (unsigned)(wn * 64 + (n0 + j) * 16 + (lane & 15));
    const unsigned off = row * 64 + ((ksw ^ ((row >> 1) & 3u)) << 4);
    bf[j] = *reinterpret_cast<const bf16x8*>((const char*)Bs + off);
  }
}

// 4-buffer lead-3 pipeline; 2 phases per K-tile; counted vmcnt never 0 mid-loop.
__device__ __forceinline__ void gemm_pipe32(const char* Ab, const char* Bb, int ldA, int ldB,
                                            int NT, unsigned short* AsAll, unsigned short* BsAll,
                                            int tid, int wm, int wn, int lane,
                                            f32x4 (&acc)[8][4]) {
#pragma unroll
  for (int t = 0; t < 3; ++t) {
    stage_op(Ab, ldA, t, AsAll + t * TILE_USH, tid);
    stage_op(Bb, ldB, t, BsAll + t * TILE_USH, tid);
  }
  asm volatile("s_waitcnt vmcnt(8)" ::: "memory");
  __builtin_amdgcn_s_barrier();
  __builtin_amdgcn_sched_barrier(0);
  for (int kt = 0; kt < NT; ++kt) {
    const int bk = kt & 3;
    const unsigned short* As = AsAll + bk * TILE_USH;
    const unsigned short* Bs = BsAll + bk * TILE_USH;
    const int bs = (kt + 3) & 3;
    bf16x8 af[8], b01[2], b23[2];
    // ---- Phase A: ds-read A frags + B n0-1, stage next A-half, 16 MFMA ----
    ldsA8(As, wm, lane, af);
    ldsB2(Bs, wn, 0, lane, b01);
    if (kt + 3 < NT) stage_op(Ab, ldA, kt + 3, AsAll + bs * TILE_USH, tid);
    __builtin_amdgcn_s_barrier();
    asm volatile("s_waitcnt lgkmcnt(0)" ::: "memory");
    __builtin_amdgcn_sched_barrier(0);
    __builtin_amdgcn_s_setprio(1);
#pragma unroll
    for (int m = 0; m < 8; ++m) {
      acc[m][0] = __builtin_amdgcn_mfma_f32_16x16x32_bf16(af[m], b01[0], acc[m][0], 0, 0, 0);
      acc[m][1] = __builtin_amdgcn_mfma_f32_16x16x32_bf16(af[m], b01[1], acc[m][1], 0, 0, 0);
    }
    __builtin_amdgcn_s_setprio(0);
    __builtin_amdgcn_s_barrier();
    // ---- Phase B: ds-read B n2-3, stage next B-half, 16 MFMA ----
    ldsB2(Bs, wn, 2, lane, b23);
    if (kt + 3 < NT) stage_op(Bb, ldB, kt + 3, BsAll + bs * TILE_USH, tid);
    __builtin_amdgcn_s_barrier();
    asm volatile("s_waitcnt lgkmcnt(0)" ::: "memory");
    __builtin_amdgcn_sched_barrier(0);
    __builtin_amdgcn_s_setprio(1);
#pragma unroll
    for (int m = 0; m < 8; ++m) {
      acc[m][2] = __builtin_amdgcn_mfma_f32_16x16x32_bf16(af[m], b23[0], acc[m][2], 0, 0, 0);
      acc[m][3] = __builtin_amdgcn_mfma_f32_16x16x32_bf16(af[m], b23[1], acc[m][3], 0, 0, 0);
    }
    __builtin_amdgcn_s_setprio(0);
    if (kt + 1 < NT) {
      if (kt + 3 < NT)       asm volatile("s_waitcnt vmcnt(8)" ::: "memory");
      else if (kt + 3 == NT) asm volatile("s_waitcnt vmcnt(4)" ::: "memory");
      else                   asm volatile("s_waitcnt vmcnt(0)" ::: "memory");
      __builtin_amdgcn_s_barrier();
      __builtin_amdgcn_sched_barrier(0);
    }
  }
}

// ---------------- K0: f32->bf16 conversion (q,k,v,W) + mask bit-pack ----------------
__global__ __launch_bounds__(256) void k_cvt(const float* __restrict__ q,
                                             const float* __restrict__ k,
                                             const float* __restrict__ v,
                                             const float* __restrict__ W,
                                             const int* __restrict__ mask,
                                             unsigned short* __restrict__ qb,
                                             unsigned short* __restrict__ kb,
                                             unsigned short* __restrict__ vb,
                                             unsigned short* __restrict__ Wb,
                                             unsigned long long* __restrict__ mbits) {
  const int y = blockIdx.y;
  if (y == 4) {
    const int nwords = B_ * S_ * (S_ / 64);  // 524288
    const int wave = (blockIdx.x * 256 + threadIdx.x) >> 6;
    const int lane = threadIdx.x & 63;
    const int nwaves = gridDim.x * 4;
    for (int w = wave; w < nwords; w += nwaves) {
      int mk = mask[(size_t)w * 64 + lane];
      unsigned long long bal = __ballot(mk == 1);
      if (lane == 0) mbits[w] = bal;
    }
    return;
  }
  const float* src = (y == 0) ? q : (y == 1) ? k : (y == 2) ? v : W;
  unsigned short* dst = (y == 0) ? qb : (y == 1) ? kb : (y == 2) ? vb : Wb;
  const int n4 = (y < 3) ? (B_ * S_ * E_ / 4) : (E_ * E_ / 4);
  const int stride = gridDim.x * 256;
  for (int i = blockIdx.x * 256 + threadIdx.x; i < n4; i += stride) {
    float4 f = reinterpret_cast<const float4*>(src)[i];
    uint2 p;
    p.x = pk2bf(f.x, f.y);
    p.y = pk2bf(f.z, f.w);
    reinterpret_cast<uint2*>(dst)[i] = p;
  }
}

// ---------------- K1: projection GEMM  O = Xb @ Wb^T + b  (bf16 in/out) -------------
__global__ __launch_bounds__(512, 1) void k_projb(const unsigned short* __restrict__ Xb,
                                                  const unsigned short* __restrict__ Wb,
                                                  const float* __restrict__ bias,
                                                  unsigned short* __restrict__ qp,
                                                  unsigned short* __restrict__ kp,
                                                  unsigned short* __restrict__ vp) {
  __shared__ __attribute__((aligned(16))) unsigned short AsAll[4 * TILE_USH];  // 64 KB
  __shared__ __attribute__((aligned(16))) unsigned short BsAll[4 * TILE_USH];  // 64 KB
  const int tid = threadIdx.x, lane = tid & 63, wid = tid >> 6;
  const int wm = wid >> 2, wn = wid & 3;
  const int c0 = blockIdx.x * 256, r0 = blockIdx.y * 256, z = blockIdx.z;
  const unsigned short* X = Xb + (size_t)z * (B_ * S_ * E_);
  unsigned short* O = (z == 0) ? qp : ((z == 1) ? kp : vp);

  const char* Ab = (const char*)(X + (size_t)r0 * E_);
  const char* Bb = (const char*)(Wb + (size_t)c0 * E_);
  f32x4 acc[8][4] = {};
  gemm_pipe32(Ab, Bb, E_ * 2, E_ * 2, E_ / 32, AsAll, BsAll, tid, wm, wn, lane, acc);

  float bcol[4];
#pragma unroll
  for (int n = 0; n < 4; ++n) bcol[n] = bias[c0 + wn * 64 + n * 16 + (lane & 15)];
#pragma unroll
  for (int m = 0; m < 8; ++m)
#pragma unroll
    for (int r = 0; r < 4; ++r) {
      const int row = r0 + wm * 128 + m * 16 + (lane >> 4) * 4 + r;
#pragma unroll
      for (int n = 0; n < 4; ++n) {
        const int col = c0 + wn * 64 + n * 16 + (lane & 15);
        O[(size_t)row * E_ + col] = (unsigned short)pk2bf(acc[m][n][r] + bcol[n], 0.f);
      }
    }
}

// ---------------- K1b: transpose vp [B*S][E] -> vpT [B][E][S] ------------------------
__global__ __launch_bounds__(256) void k_vtrans(const unsigned short* __restrict__ vp,
                                                unsigned short* __restrict__ vpT) {
  __shared__ __attribute__((aligned(16))) unsigned short t[64][72];
  const int tid = threadIdx.x;
  const int st = blockIdx.x;
  const int ot = blockIdx.y;
  const int b = blockIdx.z;
#pragma unroll
  for (int i = 0; i < 2; ++i) {
    int f = i * 256 + tid;
    int s = f >> 3, c8 = f & 7;
    uint4 vv = *reinterpret_cast<const uint4*>(
        &vp[((size_t)b * S_ + st * 64 + s) * E_ + ot * 64 + c8 * 8]);
    *reinterpret_cast<uint4*>(&t[s][c8 * 8]) = vv;
  }
  __syncthreads();
  const int o = tid >> 2;
  const int sb = (tid & 3) * 16;
  unsigned p[8];
#pragma unroll
  for (int j = 0; j < 8; ++j)
    p[j] = (unsigned)t[sb + 2 * j][o] | ((unsigned)t[sb + 2 * j + 1][o] << 16);
  uint4 w0 = make_uint4(p[0], p[1], p[2], p[3]);
  uint4 w1 = make_uint4(p[4], p[5], p[6], p[7]);
  size_t ob = ((size_t)b * E_ + ot * 64 + o) * S_ + st * 64 + sb;
  *reinterpret_cast<uint4*>(&vpT[ob]) = w0;
  *reinterpret_cast<uint4*>(&vpT[ob + 8]) = w1;
}

// ---------------- K2: scores tile GEMM + mask + exp (unnormalized) + rowsum ---------
__global__ __launch_bounds__(512, 1) void k_scores(const unsigned short* __restrict__ qp,
                                                   const unsigned short* __restrict__ kp,
                                                   const unsigned* __restrict__ mbits,
                                                   unsigned short* __restrict__ P,
                                                   float* __restrict__ rowsum) {
  __shared__ __attribute__((aligned(16))) unsigned short AsAll[4 * TILE_USH];
  __shared__ __attribute__((aligned(16))) unsigned short BsAll[4 * TILE_USH];
  __shared__ float rlds[256][4];
  const int tid = threadIdx.x, lane = tid & 63, wid = tid >> 6;
  const int wm = wid >> 2, wn = wid & 3;
  const int yt = blockIdx.x, qt = blockIdx.y, b = blockIdx.z;
  const char* Ab = (const char*)(qp + ((size_t)b * S_ + qt * 256) * E_);
  const char* Bb = (const char*)(kp + ((size_t)b * S_ + yt * 256) * E_);
  f32x4 acc[8][4] = {};
  gemm_pipe32(Ab, Bb, E_ * 2, E_ * 2, E_ / 32, AsAll, BsAll, tid, wm, wn, lane, acc);

  const float SC = (float)(1.4426950408889634 / 27.712812921102035);  // log2(e)/sqrt(768)
#pragma unroll
  for (int m = 0; m < 8; ++m)
#pragma unroll
    for (int r = 0; r < 4; ++r) {
      const int rloc = wm * 128 + m * 16 + (lane >> 4) * 4 + r;
      const int grow = qt * 256 + rloc;
      const size_t rowoff = ((size_t)b * S_ + grow) * S_;
      const uint2 mb = *reinterpret_cast<const uint2*>(
          &mbits[((size_t)b * S_ + grow) * 64 + yt * 8 + wn * 2]);
      const int cbase = yt * 256 + wn * 64 + (lane & 15);
      float radd = 0.f;
#pragma unroll
      for (int n = 0; n < 4; ++n) {
        const unsigned wsel = (n & 2) ? mb.y : mb.x;
        const int sh = (lane & 15) + ((n & 1) << 4);
        float pv = ((wsel >> sh) & 1u) ? 0.f : __builtin_amdgcn_exp2f(acc[m][n][r] * SC);
        radd += pv;
        P[rowoff + cbase + n * 16] = (unsigned short)pk2bf(pv, 0.f);
      }
      float vsum = radd;
      vsum += __shfl_xor(vsum, 1);
      vsum += __shfl_xor(vsum, 2);
      vsum += __shfl_xor(vsum, 4);
      vsum += __shfl_xor(vsum, 8);
      if ((lane & 15) == 0) rlds[rloc][wn] = vsum;
    }
  __syncthreads();
  if (tid < 256) {
    rowsum[(size_t)yt * (B_ * S_) + (size_t)b * S_ + qt * 256 + tid] =
        (rlds[tid][0] + rlds[tid][1]) + (rlds[tid][2] + rlds[tid][3]);
  }
}

// ---------------- K2b: inv_rs = 1 / sum_yt rowsum -----------------------------------
__global__ __launch_bounds__(256) void k_invrs(const float* __restrict__ rowsum,
                                               float* __restrict__ inv_rs) {
  int i = blockIdx.x * 256 + threadIdx.x;
  float t = 0.f;
#pragma unroll
  for (int g = 0; g < 8; ++g) t += rowsum[(size_t)g * (B_ * S_) + i];
  inv_rs[i] = 1.0f / t;
}

// ---------------- K3: out = (P @ vpT^T) * inv_rs  (f32 out) -------------------------
__global__ __launch_bounds__(512, 1) void k_pv(const unsigned short* __restrict__ P,
                                               const unsigned short* __restrict__ vpT,
                                               const float* __restrict__ inv_rs,
                                               float* __restrict__ out) {
  __shared__ __attribute__((aligned(16))) unsigned short AsAll[4 * TILE_USH];
  __shared__ __attribute__((aligned(16))) unsigned short BsAll[4 * TILE_USH];
  const int tid = threadIdx.x, lane = tid & 63, wid = tid >> 6;
  const int wm = wid >> 2, wn = wid & 3;
  const int yt = blockIdx.x, mt = blockIdx.y, b = blockIdx.z;
  const char* Ab = (const char*)(P + ((size_t)b * S_ + mt * 256) * S_);
  const char* Bb = (const char*)(vpT + ((size_t)b * E_ + yt * 256) * S_);
  f32x4 acc[8][4] = {};
  gemm_pipe32(Ab, Bb, S_ * 2, S_ * 2, S_ / 32, AsAll, BsAll, tid, wm, wn, lane, acc);

#pragma unroll
  for (int m = 0; m < 8; ++m)
#pragma unroll
    for (int r = 0; r < 4; ++r) {
      const int grow = mt * 256 + wm * 128 + m * 16 + (lane >> 4) * 4 + r;
      const float inv = inv_rs[b * S_ + grow];
#pragma unroll
      for (int n = 0; n < 4; ++n) {
        const int col = yt * 256 + wn * 64 + n * 16 + (lane & 15);
        out[((size_t)b * S_ + grow) * E_ + col] = acc[m][n][r] * inv;
      }
    }
}

extern "C" void kernel_launch(void* const* d_in, const int* in_sizes, int n_in,
                              void* d_out, int out_size, void* d_ws, size_t ws_size,
                              hipStream_t stream) {
  const float* q = (const float*)d_in[0];
  const float* k = (const float*)d_in[1];
  const float* v = (const float*)d_in[2];
  const int* mask = (const int*)d_in[3];
  const float* W = (const float*)d_in[4];
  const float* bias = (const float*)d_in[5];
  float* out = (float*)d_out;
  char* ws = (char*)d_ws;

  // workspace layout (bytes); high-water ~145 MB
  unsigned short* qb = (unsigned short*)(ws + 0);          // 3x24MB, contiguous q,k,v
  unsigned short* kb = (unsigned short*)(ws + 25165824);
  unsigned short* vb = (unsigned short*)(ws + 50331648);
  unsigned short* Wb = (unsigned short*)(ws + 75497472);   // 1.18 MB, dead after k_projb
  unsigned short* qp = (unsigned short*)(ws + 76677120);   // 24 MB
  unsigned short* kp = (unsigned short*)(ws + 101842944);  // 24 MB
  unsigned short* vpT = (unsigned short*)(ws + 127008768); // 24 MB
  // aliases over dead regions:
  unsigned short* P = (unsigned short*)(ws + 0);           // 64 MiB over dead qb/kb/vb
  float* rowsum = (float*)(ws + 75497472);                 // 512 KB over dead Wb
  float* inv_rs = (float*)(ws + 76546048);                 // 64 KB, still inside Wb slot
  unsigned short* vp_tmp = (unsigned short*)d_out;         // 24 MB scratch; k_pv overwrites
  unsigned long long* mbits =
      (unsigned long long*)((char*)d_out + 25165824);      // 4 MB in d_out; dead before k_pv
  (void)in_sizes; (void)n_in; (void)out_size; (void)ws_size;

  dim3 blk(256, 1, 1);
  dim3 blk2(512, 1, 1);
  k_cvt<<<dim3(512, 5, 1), blk, 0, stream>>>(q, k, v, W, mask, qb, kb, vb, Wb, mbits);
  k_projb<<<dim3(3, 64, 3), blk2, 0, stream>>>(qb, Wb, bias, qp, kp, vp_tmp);
  k_vtrans<<<dim3(32, 12, 8), blk, 0, stream>>>(vp_tmp, vpT);
  k_scores<<<dim3(8, 8, 8), blk2, 0, stream>>>(qp, kp, (const unsigned*)mbits, P, rowsum);
  k_invrs<<<dim3(64, 1, 1), blk, 0, stream>>>(rowsum, inv_rs);
  k_pv<<<dim3(3, 8, 8), blk2, 0, stream>>>(P, vpT, inv_rs, out);
}

// Round 8
// 327.020 us; speedup vs baseline: 1.2897x; 1.2897x over previous
//
#include <hip/hip_runtime.h>
#include <hip/hip_bf16.h>
#include <stdint.h>

#define B_ 8
#define S_ 2048
#define E_ 768

typedef __attribute__((ext_vector_type(4))) float f32x4;
typedef __attribute__((ext_vector_type(8))) short bf16x8;

// GEMM core: BM=256, BN=256, BK=32, 512 thr (8 waves 2Mx4N, 128x64 per wave)
// LDS: 4 buffers x (A 16KB + B 16KB) = 128 KB, lead-3 prefetch, vmcnt(8),
// 2 fine phases per K-tile (16 MFMA each) with per-phase barrier pairs.
#define TILE_USH (256 * 32)  // 16 KB per operand per buffer

__device__ __forceinline__ unsigned pk2bf(float x, float y) {
  unsigned r;
  asm("v_cvt_pk_bf16_f32 %0, %1, %2" : "=v"(r) : "v"(x), "v"(y));
  return r;
}

__device__ __forceinline__ void gll16(const void* g, void* l) {
  __builtin_amdgcn_global_load_lds((const __attribute__((address_space(1))) void*)g,
                                   (__attribute__((address_space(3))) void*)l, 16, 0, 0);
}

// Swizzle for 64B rows (32 bf16): chunk' = chunk ^ ((row>>1)&3).
// Staging: LDS dest linear, global SOURCE pre-swizzled (involution, rule #21).
__device__ __forceinline__ void stage_op(const char* Gb, int ld, int kt,
                                         unsigned short* Ls, int tid) {
#pragma unroll
  for (int i = 0; i < 2; ++i) {
    const unsigned lin = (unsigned)i * 8192u + (unsigned)tid * 16u;
    const unsigned row = lin >> 6;
    const unsigned chunk = (lin >> 4) & 3u;
    const unsigned sw = (chunk ^ ((row >> 1) & 3u)) << 4;
    gll16(Gb + (size_t)row * ld + (size_t)kt * 64 + sw, (char*)Ls + lin);
  }
}

__device__ __forceinline__ void ldsA8(const unsigned short* As, int wm, int lane,
                                      bf16x8 (&af)[8]) {
  const unsigned ksw = (unsigned)(lane >> 4);
#pragma unroll
  for (int m = 0; m < 8; ++m) {
    const unsigned row = (unsigned)(wm * 128 + m * 16 + (lane & 15));
    const unsigned off = row * 64 + ((ksw ^ ((row >> 1) & 3u)) << 4);
    af[m] = *reinterpret_cast<const bf16x8*>((const char*)As + off);
  }
}

__device__ __forceinline__ void ldsB2(const unsigned short* Bs, int wn, int n0, int lane,
                                      bf16x8 (&bf)[2]) {
  const unsigned ksw = (unsigned)(lane >> 4);
#pragma unroll
  for (int j = 0; j < 2; ++j) {
    const unsigned row = (unsigned)(wn * 64 + (n0 + j) * 16 + (lane & 15));
    const unsigned off = row * 64 + ((ksw ^ ((row >> 1) & 3u)) << 4);
    bf[j] = *reinterpret_cast<const bf16x8*>((const char*)Bs + off);
  }
}

// 4-buffer lead-3 pipeline; 2 phases per K-tile; counted vmcnt never 0 mid-loop.
__device__ __forceinline__ void gemm_pipe32(const char* Ab, const char* Bb, int ldA, int ldB,
                                            int NT, unsigned short* AsAll, unsigned short* BsAll,
                                            int tid, int wm, int wn, int lane,
                                            f32x4 (&acc)[8][4]) {
#pragma unroll
  for (int t = 0; t < 3; ++t) {
    stage_op(Ab, ldA, t, AsAll + t * TILE_USH, tid);
    stage_op(Bb, ldB, t, BsAll + t * TILE_USH, tid);
  }
  asm volatile("s_waitcnt vmcnt(8)" ::: "memory");
  __builtin_amdgcn_s_barrier();
  __builtin_amdgcn_sched_barrier(0);
  for (int kt = 0; kt < NT; ++kt) {
    const int bk = kt & 3;
    const unsigned short* As = AsAll + bk * TILE_USH;
    const unsigned short* Bs = BsAll + bk * TILE_USH;
    const int bs = (kt + 3) & 3;
    bf16x8 af[8], b01[2], b23[2];
    // ---- Phase A: ds-read A frags + B n0-1, stage next A-half, 16 MFMA ----
    ldsA8(As, wm, lane, af);
    ldsB2(Bs, wn, 0, lane, b01);
    if (kt + 3 < NT) stage_op(Ab, ldA, kt + 3, AsAll + bs * TILE_USH, tid);
    __builtin_amdgcn_s_barrier();
    asm volatile("s_waitcnt lgkmcnt(0)" ::: "memory");
    __builtin_amdgcn_sched_barrier(0);
    __builtin_amdgcn_s_setprio(1);
#pragma unroll
    for (int m = 0; m < 8; ++m) {
      acc[m][0] = __builtin_amdgcn_mfma_f32_16x16x32_bf16(af[m], b01[0], acc[m][0], 0, 0, 0);
      acc[m][1] = __builtin_amdgcn_mfma_f32_16x16x32_bf16(af[m], b01[1], acc[m][1], 0, 0, 0);
    }
    __builtin_amdgcn_s_setprio(0);
    __builtin_amdgcn_s_barrier();
    // ---- Phase B: ds-read B n2-3, stage next B-half, 16 MFMA ----
    ldsB2(Bs, wn, 2, lane, b23);
    if (kt + 3 < NT) stage_op(Bb, ldB, kt + 3, BsAll + bs * TILE_USH, tid);
    __builtin_amdgcn_s_barrier();
    asm volatile("s_waitcnt lgkmcnt(0)" ::: "memory");
    __builtin_amdgcn_sched_barrier(0);
    __builtin_amdgcn_s_setprio(1);
#pragma unroll
    for (int m = 0; m < 8; ++m) {
      acc[m][2] = __builtin_amdgcn_mfma_f32_16x16x32_bf16(af[m], b23[0], acc[m][2], 0, 0, 0);
      acc[m][3] = __builtin_amdgcn_mfma_f32_16x16x32_bf16(af[m], b23[1], acc[m][3], 0, 0, 0);
    }
    __builtin_amdgcn_s_setprio(0);
    if (kt + 1 < NT) {
      if (kt + 3 < NT)       asm volatile("s_waitcnt vmcnt(8)" ::: "memory");
      else if (kt + 3 == NT) asm volatile("s_waitcnt vmcnt(4)" ::: "memory");
      else                   asm volatile("s_waitcnt vmcnt(0)" ::: "memory");
      __builtin_amdgcn_s_barrier();
      __builtin_amdgcn_sched_barrier(0);
    }
  }
}

// ---------------- K0: f32->bf16 conversion (q,k,v,W) + mask bit-pack ----------------
// Pack layout (permuted, self-consistent): chunk c covers mask[c*256..c*256+255];
// bit L of word mwords[c*4+j] = (mask[c*256 + L*4 + j] == 1).
__global__ __launch_bounds__(256) void k_cvt(const float* __restrict__ q,
                                             const float* __restrict__ k,
                                             const float* __restrict__ v,
                                             const float* __restrict__ W,
                                             const int* __restrict__ mask,
                                             unsigned short* __restrict__ qb,
                                             unsigned short* __restrict__ kb,
                                             unsigned short* __restrict__ vb,
                                             unsigned short* __restrict__ Wb,
                                             unsigned long long* __restrict__ mwords) {
  const int y = blockIdx.y;
  if (y == 4) {
    const int nchunks = B_ * S_ * (S_ / 256);  // 131072
    const int lane = threadIdx.x & 63;
    const int wave = (blockIdx.x * 256 + threadIdx.x) >> 6;
    const int nw = gridDim.x * 4;
    int c = wave;
    for (; c + 3 * nw < nchunks; c += 4 * nw) {
      int4 v0 = *reinterpret_cast<const int4*>(&mask[(size_t)c * 256 + lane * 4]);
      int4 v1 = *reinterpret_cast<const int4*>(&mask[(size_t)(c + nw) * 256 + lane * 4]);
      int4 v2 = *reinterpret_cast<const int4*>(&mask[(size_t)(c + 2 * nw) * 256 + lane * 4]);
      int4 v3 = *reinterpret_cast<const int4*>(&mask[(size_t)(c + 3 * nw) * 256 + lane * 4]);
      unsigned long long a0 = __ballot(v0.x == 1), a1 = __ballot(v0.y == 1);
      unsigned long long a2 = __ballot(v0.z == 1), a3 = __ballot(v0.w == 1);
      unsigned long long b0 = __ballot(v1.x == 1), b1 = __ballot(v1.y == 1);
      unsigned long long b2 = __ballot(v1.z == 1), b3 = __ballot(v1.w == 1);
      unsigned long long c0 = __ballot(v2.x == 1), c1 = __ballot(v2.y == 1);
      unsigned long long c2 = __ballot(v2.z == 1), c3 = __ballot(v2.w == 1);
      unsigned long long d0 = __ballot(v3.x == 1), d1 = __ballot(v3.y == 1);
      unsigned long long d2 = __ballot(v3.z == 1), d3 = __ballot(v3.w == 1);
      if (lane == 0) {
        *reinterpret_cast<ulonglong2*>(&mwords[(size_t)c * 4]) = make_ulonglong2(a0, a1);
        *reinterpret_cast<ulonglong2*>(&mwords[(size_t)c * 4 + 2]) = make_ulonglong2(a2, a3);
        *reinterpret_cast<ulonglong2*>(&mwords[(size_t)(c + nw) * 4]) = make_ulonglong2(b0, b1);
        *reinterpret_cast<ulonglong2*>(&mwords[(size_t)(c + nw) * 4 + 2]) = make_ulonglong2(b2, b3);
        *reinterpret_cast<ulonglong2*>(&mwords[(size_t)(c + 2 * nw) * 4]) = make_ulonglong2(c0, c1);
        *reinterpret_cast<ulonglong2*>(&mwords[(size_t)(c + 2 * nw) * 4 + 2]) = make_ulonglong2(c2, c3);
        *reinterpret_cast<ulonglong2*>(&mwords[(size_t)(c + 3 * nw) * 4]) = make_ulonglong2(d0, d1);
        *reinterpret_cast<ulonglong2*>(&mwords[(size_t)(c + 3 * nw) * 4 + 2]) = make_ulonglong2(d2, d3);
      }
    }
    for (; c < nchunks; c += nw) {
      int4 v0 = *reinterpret_cast<const int4*>(&mask[(size_t)c * 256 + lane * 4]);
      unsigned long long a0 = __ballot(v0.x == 1), a1 = __ballot(v0.y == 1);
      unsigned long long a2 = __ballot(v0.z == 1), a3 = __ballot(v0.w == 1);
      if (lane == 0) {
        *reinterpret_cast<ulonglong2*>(&mwords[(size_t)c * 4]) = make_ulonglong2(a0, a1);
        *reinterpret_cast<ulonglong2*>(&mwords[(size_t)c * 4 + 2]) = make_ulonglong2(a2, a3);
      }
    }
    return;
  }
  const float* src = (y == 0) ? q : (y == 1) ? k : (y == 2) ? v : W;
  unsigned short* dst = (y == 0) ? qb : (y == 1) ? kb : (y == 2) ? vb : Wb;
  const int n4 = (y < 3) ? (B_ * S_ * E_ / 4) : (E_ * E_ / 4);
  const int stride = gridDim.x * 256;
  const float4* s4 = reinterpret_cast<const float4*>(src);
  uint2* d2 = reinterpret_cast<uint2*>(dst);
  int i = blockIdx.x * 256 + threadIdx.x;
  for (; i + 3 * stride < n4; i += 4 * stride) {
    float4 f0 = s4[i];
    float4 f1 = s4[i + stride];
    float4 f2 = s4[i + 2 * stride];
    float4 f3 = s4[i + 3 * stride];
    d2[i]              = make_uint2(pk2bf(f0.x, f0.y), pk2bf(f0.z, f0.w));
    d2[i + stride]     = make_uint2(pk2bf(f1.x, f1.y), pk2bf(f1.z, f1.w));
    d2[i + 2 * stride] = make_uint2(pk2bf(f2.x, f2.y), pk2bf(f2.z, f2.w));
    d2[i + 3 * stride] = make_uint2(pk2bf(f3.x, f3.y), pk2bf(f3.z, f3.w));
  }
  for (; i < n4; i += stride) {
    float4 f0 = s4[i];
    d2[i] = make_uint2(pk2bf(f0.x, f0.y), pk2bf(f0.z, f0.w));
  }
}

// ---------------- K1: projection GEMM  O = Xb @ Wb^T + b  (bf16 in/out) -------------
__global__ __launch_bounds__(512, 1) void k_projb(const unsigned short* __restrict__ Xb,
                                                  const unsigned short* __restrict__ Wb,
                                                  const float* __restrict__ bias,
                                                  unsigned short* __restrict__ qp,
                                                  unsigned short* __restrict__ kp,
                                                  unsigned short* __restrict__ vp) {
  __shared__ __attribute__((aligned(16))) unsigned short AsAll[4 * TILE_USH];  // 64 KB
  __shared__ __attribute__((aligned(16))) unsigned short BsAll[4 * TILE_USH];  // 64 KB
  const int tid = threadIdx.x, lane = tid & 63, wid = tid >> 6;
  const int wm = wid >> 2, wn = wid & 3;
  const int c0 = blockIdx.x * 256, r0 = blockIdx.y * 256, z = blockIdx.z;
  const unsigned short* X = Xb + (size_t)z * (B_ * S_ * E_);
  unsigned short* O = (z == 0) ? qp : ((z == 1) ? kp : vp);

  const char* Ab = (const char*)(X + (size_t)r0 * E_);
  const char* Bb = (const char*)(Wb + (size_t)c0 * E_);
  f32x4 acc[8][4] = {};
  gemm_pipe32(Ab, Bb, E_ * 2, E_ * 2, E_ / 32, AsAll, BsAll, tid, wm, wn, lane, acc);

  float bcol[4];
#pragma unroll
  for (int n = 0; n < 4; ++n) bcol[n] = bias[c0 + wn * 64 + n * 16 + (lane & 15)];
#pragma unroll
  for (int m = 0; m < 8; ++m)
#pragma unroll
    for (int r = 0; r < 4; ++r) {
      const int row = r0 + wm * 128 + m * 16 + (lane >> 4) * 4 + r;
#pragma unroll
      for (int n = 0; n < 4; ++n) {
        const int col = c0 + wn * 64 + n * 16 + (lane & 15);
        O[(size_t)row * E_ + col] = (unsigned short)pk2bf(acc[m][n][r] + bcol[n], 0.f);
      }
    }
}

// ---------------- K1b: transpose vp [B*S][E] -> vpT [B][E][S] ------------------------
__global__ __launch_bounds__(256) void k_vtrans(const unsigned short* __restrict__ vp,
                                                unsigned short* __restrict__ vpT) {
  __shared__ __attribute__((aligned(16))) unsigned short t[64][72];
  const int tid = threadIdx.x;
  const int st = blockIdx.x;
  const int ot = blockIdx.y;
  const int b = blockIdx.z;
#pragma unroll
  for (int i = 0; i < 2; ++i) {
    int f = i * 256 + tid;
    int s = f >> 3, c8 = f & 7;
    uint4 vv = *reinterpret_cast<const uint4*>(
        &vp[((size_t)b * S_ + st * 64 + s) * E_ + ot * 64 + c8 * 8]);
    *reinterpret_cast<uint4*>(&t[s][c8 * 8]) = vv;
  }
  __syncthreads();
  const int o = tid >> 2;
  const int sb = (tid & 3) * 16;
  unsigned p[8];
#pragma unroll
  for (int j = 0; j < 8; ++j)
    p[j] = (unsigned)t[sb + 2 * j][o] | ((unsigned)t[sb + 2 * j + 1][o] << 16);
  uint4 w0 = make_uint4(p[0], p[1], p[2], p[3]);
  uint4 w1 = make_uint4(p[4], p[5], p[6], p[7]);
  size_t ob = ((size_t)b * E_ + ot * 64 + o) * S_ + st * 64 + sb;
  *reinterpret_cast<uint4*>(&vpT[ob]) = w0;
  *reinterpret_cast<uint4*>(&vpT[ob + 8]) = w1;
}

// ---------------- K2: scores tile GEMM + mask + exp (unnormalized) + rowsum ---------
__global__ __launch_bounds__(512, 1) void k_scores(const unsigned short* __restrict__ qp,
                                                   const unsigned short* __restrict__ kp,
                                                   const unsigned long long* __restrict__ mwords,
                                                   unsigned short* __restrict__ P,
                                                   float* __restrict__ rowsum) {
  __shared__ __attribute__((aligned(16))) unsigned short AsAll[4 * TILE_USH];
  __shared__ __attribute__((aligned(16))) unsigned short BsAll[4 * TILE_USH];
  __shared__ float rlds[256][4];
  const int tid = threadIdx.x, lane = tid & 63, wid = tid >> 6;
  const int wm = wid >> 2, wn = wid & 3;
  const int yt = blockIdx.x, qt = blockIdx.y, b = blockIdx.z;
  const char* Ab = (const char*)(qp + ((size_t)b * S_ + qt * 256) * E_);
  const char* Bb = (const char*)(kp + ((size_t)b * S_ + yt * 256) * E_);
  f32x4 acc[8][4] = {};
  gemm_pipe32(Ab, Bb, E_ * 2, E_ * 2, E_ / 32, AsAll, BsAll, tid, wm, wn, lane, acc);

  const float SC = (float)(1.4426950408889634 / 27.712812921102035);  // log2(e)/sqrt(768)
#pragma unroll
  for (int m = 0; m < 8; ++m)
#pragma unroll
    for (int r = 0; r < 4; ++r) {
      const int rloc = wm * 128 + m * 16 + (lane >> 4) * 4 + r;
      const int grow = qt * 256 + rloc;
      const size_t rowoff = ((size_t)b * S_ + grow) * S_;
      // chunk = (b*S+grow)*8 + yt ; word j = lane&3 ; bit = wn*16 + n*4 + ((lane&15)>>2)
      const unsigned long long mw =
          mwords[(((size_t)b * S_ + grow) * 8 + yt) * 4 + (lane & 3)];
      const int shb = wn * 16 + ((lane & 15) >> 2);
      const int cbase = yt * 256 + wn * 64 + (lane & 15);
      float radd = 0.f;
#pragma unroll
      for (int n = 0; n < 4; ++n) {
        float pv = ((mw >> (shb + n * 4)) & 1ull)
                       ? 0.f
                       : __builtin_amdgcn_exp2f(acc[m][n][r] * SC);
        radd += pv;
        P[rowoff + cbase + n * 16] = (unsigned short)pk2bf(pv, 0.f);
      }
      float vsum = radd;
      vsum += __shfl_xor(vsum, 1);
      vsum += __shfl_xor(vsum, 2);
      vsum += __shfl_xor(vsum, 4);
      vsum += __shfl_xor(vsum, 8);
      if ((lane & 15) == 0) rlds[rloc][wn] = vsum;
    }
  __syncthreads();
  if (tid < 256) {
    rowsum[(size_t)yt * (B_ * S_) + (size_t)b * S_ + qt * 256 + tid] =
        (rlds[tid][0] + rlds[tid][1]) + (rlds[tid][2] + rlds[tid][3]);
  }
}

// ---------------- K2b: inv_rs = 1 / sum_yt rowsum -----------------------------------
__global__ __launch_bounds__(256) void k_invrs(const float* __restrict__ rowsum,
                                               float* __restrict__ inv_rs) {
  int i = blockIdx.x * 256 + threadIdx.x;
  float t = 0.f;
#pragma unroll
  for (int g = 0; g < 8; ++g) t += rowsum[(size_t)g * (B_ * S_) + i];
  inv_rs[i] = 1.0f / t;
}

// ---------------- K3: out = (P @ vpT^T) * inv_rs  (f32 out) -------------------------
__global__ __launch_bounds__(512, 1) void k_pv(const unsigned short* __restrict__ P,
                                               const unsigned short* __restrict__ vpT,
                                               const float* __restrict__ inv_rs,
                                               float* __restrict__ out) {
  __shared__ __attribute__((aligned(16))) unsigned short AsAll[4 * TILE_USH];
  __shared__ __attribute__((aligned(16))) unsigned short BsAll[4 * TILE_USH];
  const int tid = threadIdx.x, lane = tid & 63, wid = tid >> 6;
  const int wm = wid >> 2, wn = wid & 3;
  const int yt = blockIdx.x, mt = blockIdx.y, b = blockIdx.z;
  const char* Ab = (const char*)(P + ((size_t)b * S_ + mt * 256) * S_);
  const char* Bb = (const char*)(vpT + ((size_t)b * E_ + yt * 256) * S_);
  f32x4 acc[8][4] = {};
  gemm_pipe32(Ab, Bb, S_ * 2, S_ * 2, S_ / 32, AsAll, BsAll, tid, wm, wn, lane, acc);

#pragma unroll
  for (int m = 0; m < 8; ++m)
#pragma unroll
    for (int r = 0; r < 4; ++r) {
      const int grow = mt * 256 + wm * 128 + m * 16 + (lane >> 4) * 4 + r;
      const float inv = inv_rs[b * S_ + grow];
#pragma unroll
      for (int n = 0; n < 4; ++n) {
        const int col = yt * 256 + wn * 64 + n * 16 + (lane & 15);
        out[((size_t)b * S_ + grow) * E_ + col] = acc[m][n][r] * inv;
      }
    }
}

extern "C" void kernel_launch(void* const* d_in, const int* in_sizes, int n_in,
                              void* d_out, int out_size, void* d_ws, size_t ws_size,
                              hipStream_t stream) {
  const float* q = (const float*)d_in[0];
  const float* k = (const float*)d_in[1];
  const float* v = (const float*)d_in[2];
  const int* mask = (const int*)d_in[3];
  const float* W = (const float*)d_in[4];
  const float* bias = (const float*)d_in[5];
  float* out = (float*)d_out;
  char* ws = (char*)d_ws;

  // workspace layout (bytes); high-water ~145 MB
  unsigned short* qb = (unsigned short*)(ws + 0);          // 3x24MB, contiguous q,k,v
  unsigned short* kb = (unsigned short*)(ws + 25165824);
  unsigned short* vb = (unsigned short*)(ws + 50331648);
  unsigned short* Wb = (unsigned short*)(ws + 75497472);   // 1.18 MB, dead after k_projb
  unsigned short* qp = (unsigned short*)(ws + 76677120);   // 24 MB
  unsigned short* kp = (unsigned short*)(ws + 101842944);  // 24 MB
  unsigned short* vpT = (unsigned short*)(ws + 127008768); // 24 MB
  // aliases over dead regions:
  unsigned short* P = (unsigned short*)(ws + 0);           // 64 MiB over dead qb/kb/vb
  float* rowsum = (float*)(ws + 75497472);                 // 512 KB over dead Wb
  float* inv_rs = (float*)(ws + 76546048);                 // 64 KB, still inside Wb slot
  unsigned short* vp_tmp = (unsigned short*)d_out;         // 24 MB scratch; k_pv overwrites
  unsigned long long* mwords =
      (unsigned long long*)((char*)d_out + 25165824);      // 4 MB in d_out; dead before k_pv
  (void)in_sizes; (void)n_in; (void)out_size; (void)ws_size;

  dim3 blk(256, 1, 1);
  dim3 blk2(512, 1, 1);
  k_cvt<<<dim3(512, 5, 1), blk, 0, stream>>>(q, k, v, W, mask, qb, kb, vb, Wb, mwords);
  k_projb<<<dim3(3, 64, 3), blk2, 0, stream>>>(qb, Wb, bias, qp, kp, vp_tmp);
  k_vtrans<<<dim3(32, 12, 8), blk, 0, stream>>>(vp_tmp, vpT);
  k_scores<<<dim3(8, 8, 8), blk2, 0, stream>>>(qp, kp, mwords, P, rowsum);
  k_invrs<<<dim3(64, 1, 1), blk, 0, stream>>>(rowsum, inv_rs);
  k_pv<<<dim3(3, 8, 8), blk2, 0, stream>>>(P, vpT, inv_rs, out);
}